// Round 6
// baseline (699.734 us; speedup 1.0000x reference)
//
#include <hip/hip_runtime.h>
#include <hip/hip_bf16.h>
#include <stdint.h>

typedef __attribute__((ext_vector_type(8))) short bf16x8;
typedef __attribute__((ext_vector_type(16))) float f32x16;

__device__ __forceinline__ unsigned short f2bf(float f) {
  union { float f; unsigned int u; } v; v.f = f;
  unsigned int u = v.u;
  u += 0x7fffu + ((u >> 16) & 1u);
  return (unsigned short)(u >> 16);
}

// ---------- X transform: [512,256,20,20] f32 -> Xt [512,400,256] bf16 ----------
__global__ __launch_bounds__(256) void xform_x(const float* __restrict__ X,
                                               unsigned short* __restrict__ Xt) {
  const int b = blockIdx.x;
  const int t = threadIdx.x;  // = ci
  const float* src = X + ((size_t)b * 256 + t) * 400;
  unsigned short* dst = Xt + (size_t)b * 400 * 256 + t;
  for (int hw = 0; hw < 400; hw += 4) {
    float4 v = *(const float4*)(src + hw);
    dst[(size_t)(hw + 0) * 256] = f2bf(v.x);
    dst[(size_t)(hw + 1) * 256] = f2bf(v.y);
    dst[(size_t)(hw + 2) * 256] = f2bf(v.z);
    dst[(size_t)(hw + 3) * 256] = f2bf(v.w);
  }
}

// ---------- W transform: [256co][256ci][81] f32 -> Wt [81][256co][256ci] bf16 ----------
__global__ __launch_bounds__(256) void xform_w(const float* __restrict__ W,
                                               unsigned short* __restrict__ Wt) {
  __shared__ unsigned short lds[81 * 128];
  const int co = blockIdx.x;       // 0..255
  const int ct = blockIdx.y;       // 0..1 (ci tile of 128)
  const int t = threadIdx.x;
  const float* src = W + ((size_t)co * 256 + (size_t)ct * 128) * 81;
  for (int idx = t; idx < 128 * 81; idx += 256) {
    int ci_l = idx / 81, khw = idx - ci_l * 81;
    lds[khw * 128 + ci_l] = f2bf(src[idx]);   // src read is fully linear
  }
  __syncthreads();
  unsigned short* dst = Wt + (size_t)co * 256 + (size_t)ct * 128;
  for (int idx = t; idx < 81 * 128; idx += 256) {
    int khw = idx >> 7, ci_l = idx & 127;
    dst[(size_t)khw * 65536 + ci_l] = lds[idx];  // coalesced 128-elem rows
  }
}

// ---------- implicit-GEMM conv + bias ----------
// M = 18432 (b,oh,ow), N = 256 (co), K = 81*256 in order (kh,kw,ci)
// BM=128 BN=64 BK=64. 2 waves/block (128 thr), wave tile 64x64 via
// 2x2 x mfma_f32_32x32x16_bf16. A: LDS (read exactly once), swizzled r1
// pattern. B: direct global->VGPR (L2-resident, 2.65MB/nt), double-buffered
// regs, loads issued before the MFMA cluster. Plain __syncthreads() 2x/step
// (r1 discipline: best cache behavior + no race).
__device__ __forceinline__ void gload16(const unsigned short* g, unsigned short* l) {
  __builtin_amdgcn_global_load_lds(
      (const __attribute__((address_space(1))) unsigned int*)g,
      (__attribute__((address_space(3))) unsigned int*)l, 16, 0, 0);
}

__global__ __launch_bounds__(128, 2) void conv_gemm(
    const unsigned short* __restrict__ Xt,
    const unsigned short* __restrict__ Wt,
    const float* __restrict__ bias,
    float* __restrict__ Y) {
  __shared__ __align__(16) unsigned short sA[128 * 64];  // 16 KB, single buffer
  const int mt = blockIdx.x;   // 0..143
  const int nt = blockIdx.y;   // 0..3
  const int t = threadIdx.x;   // 0..127
  const int c8 = t & 7, rq = t >> 3;           // staging: 8 lanes/row, 16 rows/round
  const int swz = (c8 ^ (rq & 7)) * 8;         // pre-swizzled ci element offset

  // A staging sources (rows r*16+rq), incl. swizzle
  int xb[8];
  #pragma unroll
  for (int r = 0; r < 8; ++r) {
    int m = mt * 128 + r * 16 + rq;
    int b = m / 36, s = m - b * 36;
    int oh = s / 6, ow = s - oh * 6;
    xb[r] = ((b * 20 + 2 * oh) * 20 + 2 * ow) * 256 + swz;
  }
  // staging dest (elem units): row*64 + c8*8 == r*1024 + t*8 (linear per wave)
  const int dA = t * 8;

  const int l = t & 63, w = t >> 6;            // lane, wave (0..1)
  const int r31 = l & 31, ch = l >> 5;

  // A fragment offsets (elem units, swizzle-matched): row = w*64+i*32+r31,
  // k-chunk g = kk*2+ch stored at g^(row&7)
  int aOff[2][4];
  #pragma unroll
  for (int i = 0; i < 2; ++i)
    #pragma unroll
    for (int kk = 0; kk < 4; ++kk)
      aOff[i][kk] = (w * 64 + i * 32 + r31) * 64 + (((kk * 2 + ch) ^ (r31 & 7)) * 8);

  // B per-lane element offsets (col = r31, k-chunk = ch)
  int vB[2];
  #pragma unroll
  for (int j = 0; j < 2; ++j) vB[j] = (nt * 64 + j * 32 + r31) * 256 + ch * 8;

  f32x16 acc[2][2];
  #pragma unroll
  for (int i = 0; i < 2; ++i)
    #pragma unroll
    for (int j = 0; j < 2; ++j) acc[i][j] = (f32x16)(0.f);

  // K-walk state, split for A (stage) and B (reg load)
  int ciX = 0, kwX = 0, xo = 0;
  int ciW = 0, wo = 0;
  auto advX = [&]() {
    if (ciX < 3) { ++ciX; xo += 64; }
    else { ciX = 0;
           if (kwX < 8) { ++kwX; xo += 64; }
           else         { kwX = 0; xo += 2880; } }
  };
  auto advW = [&]() {
    if (ciW < 3) { ++ciW; wo += 64; }
    else { ciW = 0; wo += 65536 - 192; }
  };
  auto stage = [&]() {
    #pragma unroll
    for (int r = 0; r < 8; ++r) gload16(Xt + xb[r] + xo, sA + dA + r * 1024);
    advX();
  };
  auto loadB = [&](bf16x8 (&bf)[2][4]) {
    const unsigned short* base = Wt + wo;
    #pragma unroll
    for (int j = 0; j < 2; ++j)
      #pragma unroll
      for (int kk = 0; kk < 4; ++kk)
        bf[j][kk] = *(const bf16x8*)(base + vB[j] + kk * 16);
    advW();
  };
  auto compute = [&](bf16x8 (&bf)[2][4]) {
    bf16x8 fa[2][4];
    #pragma unroll
    for (int i = 0; i < 2; ++i)
      #pragma unroll
      for (int kk = 0; kk < 4; ++kk) fa[i][kk] = *(const bf16x8*)(sA + aOff[i][kk]);
    #pragma unroll
    for (int kk = 0; kk < 4; ++kk)
      #pragma unroll
      for (int i = 0; i < 2; ++i)
        #pragma unroll
        for (int j = 0; j < 2; ++j)
          acc[i][j] = __builtin_amdgcn_mfma_f32_32x32x16_bf16(
              fa[i][kk], bf[j][kk], acc[i][j], 0, 0, 0);
  };

  bf16x8 b0[2][4], b1[2][4];
  loadB(b0);                          // B(0)
  stage();                            // A(0)
  #pragma unroll 1
  for (int s = 0; s < 324; s += 2) {
    __syncthreads();                  // A(s) in LDS, B(s) in b0
    loadB(b1);                        // B(s+1), hides under compute
    compute(b0);
    __syncthreads();                  // all ds_reads of A(s) done
    stage();                          // A(s+1)
    __syncthreads();                  // A(s+1) in LDS, B(s+1) in b1
    if (s + 2 < 324) loadB(b0);       // B(s+2)
    compute(b1);
    __syncthreads();
    if (s + 2 < 324) stage();         // A(s+2)
  }

  // epilogue: 32x32 C/D layout: col = l&31, row = (e&3) + 8*(e>>2) + 4*ch
  #pragma unroll
  for (int j = 0; j < 2; ++j) {
    int co = nt * 64 + j * 32 + r31;
    float bb = bias[co];
    #pragma unroll
    for (int i = 0; i < 2; ++i) {
      #pragma unroll
      for (int e = 0; e < 16; ++e) {
        int row = (e & 3) + 8 * (e >> 2) + 4 * ch;
        int m = mt * 128 + w * 64 + i * 32 + row;
        int b = m / 36, s = m - b * 36;
        Y[((size_t)b * 256 + co) * 36 + s] = acc[i][j][e] + bb;
      }
    }
  }
}

// ---------- squash (in place on d_out): groups of 8 consecutive floats ----------
__global__ __launch_bounds__(256) void squash_k(float* __restrict__ Y) {
  const int g = blockIdx.x * 256 + threadIdx.x;  // 0..589823
  float4* p = (float4*)(Y + (size_t)g * 8);
  float4 a = p[0], b = p[1];
  float ns = a.x * a.x + a.y * a.y + a.z * a.z + a.w * a.w +
             b.x * b.x + b.y * b.y + b.z * b.z + b.w * b.w;
  float sc = ns / ((1.0f + ns) * (0.001f + sqrtf(ns)));
  a.x *= sc; a.y *= sc; a.z *= sc; a.w *= sc;
  b.x *= sc; b.y *= sc; b.z *= sc; b.w *= sc;
  p[0] = a; p[1] = b;
}

extern "C" void kernel_launch(void* const* d_in, const int* in_sizes, int n_in,
                              void* d_out, int out_size, void* d_ws, size_t ws_size,
                              hipStream_t stream) {
  const float* X = (const float*)d_in[0];     // [512,256,20,20]
  const float* W = (const float*)d_in[1];     // [256,256,9,9]
  const float* bias = (const float*)d_in[2];  // [256]
  float* Y = (float*)d_out;                   // [512,256,6,6] -> squashed

  unsigned short* Xt = (unsigned short*)d_ws;                 // 512*400*256 bf16
  unsigned short* Wt = Xt + (size_t)512 * 400 * 256;          // 81*256*256 bf16

  xform_x<<<512, 256, 0, stream>>>(X, Xt);
  xform_w<<<dim3(256, 2), 256, 0, stream>>>(W, Wt);
  conv_gemm<<<dim3(144, 4), 128, 0, stream>>>(Xt, Wt, bias, Y);
  squash_k<<<2304, 256, 0, stream>>>(Y);
}

// Round 7
// 509.754 us; speedup vs baseline: 1.3727x; 1.3727x over previous
//
#include <hip/hip_runtime.h>
#include <hip/hip_bf16.h>
#include <stdint.h>

typedef __attribute__((ext_vector_type(8))) short bf16x8;
typedef __attribute__((ext_vector_type(4))) float f32x4;

__device__ __forceinline__ unsigned short f2bf(float f) {
  union { float f; unsigned int u; } v; v.f = f;
  unsigned int u = v.u;
  u += 0x7fffu + ((u >> 16) & 1u);
  return (unsigned short)(u >> 16);
}

// ---------- X transform: [512,256,20,20] f32 -> Xt [512,400,256] bf16 ----------
__global__ __launch_bounds__(256) void xform_x(const float* __restrict__ X,
                                               unsigned short* __restrict__ Xt) {
  const int b = blockIdx.x;
  const int t = threadIdx.x;  // = ci
  const float* src = X + ((size_t)b * 256 + t) * 400;
  unsigned short* dst = Xt + (size_t)b * 400 * 256 + t;
  for (int hw = 0; hw < 400; hw += 4) {
    float4 v = *(const float4*)(src + hw);
    dst[(size_t)(hw + 0) * 256] = f2bf(v.x);
    dst[(size_t)(hw + 1) * 256] = f2bf(v.y);
    dst[(size_t)(hw + 2) * 256] = f2bf(v.z);
    dst[(size_t)(hw + 3) * 256] = f2bf(v.w);
  }
}

// ---------- W transform: [256co][256ci][81] f32 -> Wt [81][256co][256ci] bf16 ----------
__global__ __launch_bounds__(256) void xform_w(const float* __restrict__ W,
                                               unsigned short* __restrict__ Wt) {
  __shared__ unsigned short lds[81 * 128];
  const int co = blockIdx.x;       // 0..255
  const int ct = blockIdx.y;       // 0..1 (ci tile of 128)
  const int t = threadIdx.x;
  const float* src = W + ((size_t)co * 256 + (size_t)ct * 128) * 81;
  for (int idx = t; idx < 128 * 81; idx += 256) {
    int ci_l = idx / 81, khw = idx - ci_l * 81;
    lds[khw * 128 + ci_l] = f2bf(src[idx]);   // src read is fully linear
  }
  __syncthreads();
  unsigned short* dst = Wt + (size_t)co * 256 + (size_t)ct * 128;
  for (int idx = t; idx < 81 * 128; idx += 256) {
    int khw = idx >> 7, ci_l = idx & 127;
    dst[(size_t)khw * 65536 + ci_l] = lds[idx];  // coalesced 128-elem rows
  }
}

// ---------- implicit-GEMM conv + bias ----------
// M = 18432 (b,oh,ow), N = 256 (co), K = 81*256 in order (kh,kw,ci)
// BM=128 BN=64 BK=64, 4 waves (2x2). Double-buffered LDS with PLAIN
// __syncthreads only (one per K-step): the full vmcnt(0) drain at each sync
// keeps all blocks lockstep in the K-walk (L2 step-window ~1.7MB < 4MB ->
// 96% L2 hit; r5's counted-vmcnt broke lockstep -> FETCH 2.5x, slower).
// stage(s+1) is issued right after the sync and lands under compute(s).
__device__ __forceinline__ void gload16(const unsigned short* g, unsigned short* l) {
  __builtin_amdgcn_global_load_lds(
      (const __attribute__((address_space(1))) unsigned int*)g,
      (__attribute__((address_space(3))) unsigned int*)l, 16, 0, 0);
}

__global__ __launch_bounds__(256, 2) void conv_gemm(
    const unsigned short* __restrict__ Xt,
    const unsigned short* __restrict__ Wt,
    const float* __restrict__ bias,
    float* __restrict__ Y) {
  // per buffer (12288 shorts): A [128row][64ci] at 0, B [64co][64ci] at 8192
  __shared__ __align__(16) unsigned short lds[2][12288];  // 48 KB
  const int mt = blockIdx.x;   // 0..143
  const int nt = blockIdx.y;   // 0..3
  const int t = threadIdx.x;
  const int c8 = t & 7, rq = t >> 3;           // staging: 8 lanes/row, 32 rows/round
  const int swz = (c8 ^ (rq & 7)) * 8;         // pre-swizzled ci element offset

  // A staging sources (rows r*32+rq), incl. swizzle
  int xb[4];
  #pragma unroll
  for (int r = 0; r < 4; ++r) {
    int m = mt * 128 + r * 32 + rq;
    int b = m / 36, s = m - b * 36;
    int oh = s / 6, ow = s - oh * 6;
    xb[r] = ((b * 20 + 2 * oh) * 20 + 2 * ow) * 256 + swz;
  }
  int wb[2];
  #pragma unroll
  for (int r = 0; r < 2; ++r) wb[r] = (nt * 64 + r * 32 + rq) * 256 + swz;

  // staging dests within one buffer (elem units): linear, byte = row*128 + c8*16
  const int dA = t * 8;            // + r*2048
  const int dB = 8192 + t * 8;     // + r*2048

  const int lane = t & 63, wv = t >> 6;
  const int wm = (wv >> 1) * 64, wn = (wv & 1) * 32;
  const int l15 = lane & 15, l4 = lane >> 4, l7 = lane & 7;

  // fragment offsets within one buffer (elem units, swizzle-matched)
  int aOff[4][2], bOff[2][2];
  #pragma unroll
  for (int i = 0; i < 4; ++i)
    #pragma unroll
    for (int kk = 0; kk < 2; ++kk)
      aOff[i][kk] = ((wm + i * 16 + l15) * 128 +
                     ((kk * 64 + l4 * 16) ^ (l7 << 4))) / 2;
  #pragma unroll
  for (int j = 0; j < 2; ++j)
    #pragma unroll
    for (int kk = 0; kk < 2; ++kk)
      bOff[j][kk] = 8192 + ((wn + j * 16 + l15) * 128 +
                            ((kk * 64 + l4 * 16) ^ (l7 << 4))) / 2;

  f32x4 acc[4][2];
  #pragma unroll
  for (int i = 0; i < 4; ++i)
    #pragma unroll
    for (int j = 0; j < 2; ++j) acc[i][j] = (f32x4){0.f, 0.f, 0.f, 0.f};

  // K-step offsets: step s -> khw = s>>2, ci0 = (s&3)*64 (SALU incremental)
  int s_ci = 0, s_kw = 0, xo = 0, wo = 0;
  auto adv = [&]() {
    if (s_ci < 3) { ++s_ci; xo += 64; wo += 64; }
    else {
      s_ci = 0; wo += 65536 - 192;
      if (s_kw < 8) { ++s_kw; xo += 64; }          // 256 - 192
      else          { s_kw = 0; xo += 2880; }      // 12*256 - 192
    }
  };
  auto stage = [&](unsigned short* buf) {
    #pragma unroll
    for (int r = 0; r < 4; ++r) gload16(Xt + xb[r] + xo, buf + dA + r * 2048);
    #pragma unroll
    for (int r = 0; r < 2; ++r) gload16(Wt + wb[r] + wo, buf + dB + r * 2048);
  };
  auto compute = [&](const unsigned short* buf) {
    bf16x8 af[4][2], bfr[2][2];
    #pragma unroll
    for (int i = 0; i < 4; ++i)
      #pragma unroll
      for (int kk = 0; kk < 2; ++kk) af[i][kk] = *(const bf16x8*)(buf + aOff[i][kk]);
    #pragma unroll
    for (int j = 0; j < 2; ++j)
      #pragma unroll
      for (int kk = 0; kk < 2; ++kk) bfr[j][kk] = *(const bf16x8*)(buf + bOff[j][kk]);
    #pragma unroll
    for (int i = 0; i < 4; ++i)
      #pragma unroll
      for (int j = 0; j < 2; ++j) {
        acc[i][j] = __builtin_amdgcn_mfma_f32_16x16x32_bf16(
            af[i][0], bfr[j][0], acc[i][j], 0, 0, 0);
        acc[i][j] = __builtin_amdgcn_mfma_f32_16x16x32_bf16(
            af[i][1], bfr[j][1], acc[i][j], 0, 0, 0);
      }
  };

  stage(&lds[0][0]); adv();
  int p = 0;
  #pragma unroll 1
  for (int s = 0; s < 324; ++s) {
    __syncthreads();                   // buf[p] landed (full drain = lockstep)
    if (s < 323) { stage(&lds[p ^ 1][0]); adv(); }  // lands under compute(s)
    compute(&lds[p][0]);
    p ^= 1;
  }

  // epilogue: D row = (lane>>4)*4+q (m dim), col = lane&15 (co dim)
  #pragma unroll
  for (int j = 0; j < 2; ++j) {
    int co = nt * 64 + wn + j * 16 + l15;
    float bb = bias[co];
    #pragma unroll
    for (int i = 0; i < 4; ++i) {
      int m0 = mt * 128 + wm + i * 16 + l4 * 4;
      #pragma unroll
      for (int q = 0; q < 4; ++q) {
        int m = m0 + q;
        int b = m / 36, s = m - b * 36;
        Y[((size_t)b * 256 + co) * 36 + s] = acc[i][j][q] + bb;
      }
    }
  }
}

// ---------- squash (in place on d_out): groups of 8 consecutive floats ----------
__global__ __launch_bounds__(256) void squash_k(float* __restrict__ Y) {
  const int g = blockIdx.x * 256 + threadIdx.x;  // 0..589823
  float4* p = (float4*)(Y + (size_t)g * 8);
  float4 a = p[0], b = p[1];
  float ns = a.x * a.x + a.y * a.y + a.z * a.z + a.w * a.w +
             b.x * b.x + b.y * b.y + b.z * b.z + b.w * b.w;
  float sc = ns / ((1.0f + ns) * (0.001f + sqrtf(ns)));
  a.x *= sc; a.y *= sc; a.z *= sc; a.w *= sc;
  b.x *= sc; b.y *= sc; b.z *= sc; b.w *= sc;
  p[0] = a; p[1] = b;
}

extern "C" void kernel_launch(void* const* d_in, const int* in_sizes, int n_in,
                              void* d_out, int out_size, void* d_ws, size_t ws_size,
                              hipStream_t stream) {
  const float* X = (const float*)d_in[0];     // [512,256,20,20]
  const float* W = (const float*)d_in[1];     // [256,256,9,9]
  const float* bias = (const float*)d_in[2];  // [256]
  float* Y = (float*)d_out;                   // [512,256,6,6] -> squashed

  unsigned short* Xt = (unsigned short*)d_ws;                 // 512*400*256 bf16
  unsigned short* Wt = Xt + (size_t)512 * 400 * 256;          // 81*256*256 bf16

  xform_x<<<512, 256, 0, stream>>>(X, Xt);
  xform_w<<<dim3(256, 2), 256, 0, stream>>>(W, Wt);
  conv_gemm<<<dim3(144, 4), 256, 0, stream>>>(Xt, Wt, bias, Y);
  squash_k<<<2304, 256, 0, stream>>>(Y);
}

// Round 8
// 407.485 us; speedup vs baseline: 1.7172x; 1.2510x over previous
//
#include <hip/hip_runtime.h>
#include <hip/hip_bf16.h>
#include <stdint.h>

typedef __attribute__((ext_vector_type(8))) short bf16x8;
typedef __attribute__((ext_vector_type(4))) float f32x4;

__device__ __forceinline__ unsigned short f2bf(float f) {
  union { float f; unsigned int u; } v; v.f = f;
  unsigned int u = v.u;
  u += 0x7fffu + ((u >> 16) & 1u);
  return (unsigned short)(u >> 16);
}

// ---------- X transform: [512,256,20,20] f32 -> Xt [512,400,256] bf16 ----------
__global__ __launch_bounds__(256) void xform_x(const float* __restrict__ X,
                                               unsigned short* __restrict__ Xt) {
  const int b = blockIdx.x;
  const int t = threadIdx.x;  // = ci
  const float* src = X + ((size_t)b * 256 + t) * 400;
  unsigned short* dst = Xt + (size_t)b * 400 * 256 + t;
  for (int hw = 0; hw < 400; hw += 4) {
    float4 v = *(const float4*)(src + hw);
    dst[(size_t)(hw + 0) * 256] = f2bf(v.x);
    dst[(size_t)(hw + 1) * 256] = f2bf(v.y);
    dst[(size_t)(hw + 2) * 256] = f2bf(v.z);
    dst[(size_t)(hw + 3) * 256] = f2bf(v.w);
  }
}

// ---------- W transform: [256co][256ci][81] f32 -> Wt [81][256co][256ci] bf16 ----------
__global__ __launch_bounds__(256) void xform_w(const float* __restrict__ W,
                                               unsigned short* __restrict__ Wt) {
  __shared__ unsigned short lds[81 * 128];
  const int co = blockIdx.x;       // 0..255
  const int ct = blockIdx.y;       // 0..1 (ci tile of 128)
  const int t = threadIdx.x;
  const float* src = W + ((size_t)co * 256 + (size_t)ct * 128) * 81;
  for (int idx = t; idx < 128 * 81; idx += 256) {
    int ci_l = idx / 81, khw = idx - ci_l * 81;
    lds[khw * 128 + ci_l] = f2bf(src[idx]);   // src read is fully linear
  }
  __syncthreads();
  unsigned short* dst = Wt + (size_t)co * 256 + (size_t)ct * 128;
  for (int idx = t; idx < 81 * 128; idx += 256) {
    int khw = idx >> 7, ci_l = idx & 127;
    dst[(size_t)khw * 65536 + ci_l] = lds[idx];  // coalesced 128-elem rows
  }
}

// ---------- implicit-GEMM conv + bias ----------
// M = 18432 (b,oh,ow), N = 256 (co), K = 81*256 in order (kh,kw,ci)
// BM=96 BN=64 BK=128, 4 waves (2x2), wave tile 48x32.
// Grid (192,4) = 768 blocks = exactly 3.0 blocks/CU (kills the 2.25-quantization
// idle of the 310us BM=128 kernel). BK=128 halves the drain count (162 steps).
// Schedule = the ONLY cache-stable one measured (r1): single LDS buffer,
// stage -> __syncthreads (full vmcnt drain, lockstep) -> compute -> sync.
// r5/r7 proved any loads-in-flight-across-barrier schedule blows the per-XCD
// L2 halo window (FETCH 189->460MB) and runs slower.
__device__ __forceinline__ void gload16(const unsigned short* g, unsigned short* l) {
  __builtin_amdgcn_global_load_lds(
      (const __attribute__((address_space(1))) unsigned int*)g,
      (__attribute__((address_space(3))) unsigned int*)l, 16, 0, 0);
}

__global__ __launch_bounds__(256, 3) void conv_gemm(
    const unsigned short* __restrict__ Xt,
    const unsigned short* __restrict__ Wt,
    const float* __restrict__ bias,
    float* __restrict__ Y) {
  // A [96row][128ci] at 0 (12288 elem), B [64co][128ci] at 12288 (8192 elem)
  __shared__ __align__(16) unsigned short lds[20480];  // 40 KB single buffer
  const int mt = blockIdx.x;   // 0..191
  const int nt = blockIdx.y;   // 0..3
  const int t = threadIdx.x;
  const int c16 = t & 15, rq = t >> 4;          // staging: 16 lanes/row, 16 rows/round
  const int swz = (c16 ^ (rq & 7)) * 8;         // pre-swizzled ci element offset

  // A staging sources (rows r*16+rq), incl. swizzle
  int xb[6];
  #pragma unroll
  for (int r = 0; r < 6; ++r) {
    int m = mt * 96 + r * 16 + rq;
    int b = m / 36, s = m - b * 36;
    int oh = s / 6, ow = s - oh * 6;
    xb[r] = ((b * 20 + 2 * oh) * 20 + 2 * ow) * 256 + swz;
  }
  int wb[4];
  #pragma unroll
  for (int r = 0; r < 4; ++r) wb[r] = (nt * 64 + r * 16 + rq) * 256 + swz;

  // staging dests (elem units): linear, row*256B + c16*16B; per-round +2048 elem
  const int dA = t * 8;             // + r*2048
  const int dB = 12288 + t * 8;     // + r*2048

  const int lane = t & 63, wv = t >> 6;
  const int wm = (wv >> 1) * 48, wn = (wv & 1) * 32;
  const int l15 = lane & 15, l4 = lane >> 4, l7s = lane & 7;

  // fragment offsets (elem units, swizzle-matched):
  // G[row][slot] lives at LDS[row][slot ^ (row&7)], slot = kk*4 + l4 (16B units)
  int aOff[3][4], bOff[2][4];
  #pragma unroll
  for (int i = 0; i < 3; ++i)
    #pragma unroll
    for (int kk = 0; kk < 4; ++kk)
      aOff[i][kk] = (wm + i * 16 + l15) * 128 +
                    (((kk * 4 + l4) ^ (l15 & 7)) * 8);
  #pragma unroll
  for (int j = 0; j < 2; ++j)
    #pragma unroll
    for (int kk = 0; kk < 4; ++kk)
      bOff[j][kk] = 12288 + (wn + j * 16 + l15) * 128 +
                    (((kk * 4 + l4) ^ (l15 & 7)) * 8);

  f32x4 acc[3][2];
  #pragma unroll
  for (int i = 0; i < 3; ++i)
    #pragma unroll
    for (int j = 0; j < 2; ++j) acc[i][j] = (f32x4){0.f, 0.f, 0.f, 0.f};

  // K-step offsets: step s -> khw = s>>1, ci0 = (s&1)*128 (SALU incremental)
  int s_ci = 0, s_kw = 0, xo = 0, wo = 0;
  auto adv = [&]() {
    if (s_ci == 0) { s_ci = 1; xo += 128; wo += 128; }
    else {
      s_ci = 0; wo += 65536 - 128;
      if (s_kw < 8) { ++s_kw; xo += 128; }         // 256 - 128
      else          { s_kw = 0; xo += 2944; }      // 12*256 - 128
    }
  };
  auto stage = [&]() {
    #pragma unroll
    for (int r = 0; r < 6; ++r) gload16(Xt + xb[r] + xo, lds + dA + r * 2048);
    #pragma unroll
    for (int r = 0; r < 4; ++r) gload16(Wt + wb[r] + wo, lds + dB + r * 2048);
  };
  auto compute = [&]() {
    bf16x8 af[3][4], bfr[2][4];
    #pragma unroll
    for (int i = 0; i < 3; ++i)
      #pragma unroll
      for (int kk = 0; kk < 4; ++kk) af[i][kk] = *(const bf16x8*)(lds + aOff[i][kk]);
    #pragma unroll
    for (int j = 0; j < 2; ++j)
      #pragma unroll
      for (int kk = 0; kk < 4; ++kk) bfr[j][kk] = *(const bf16x8*)(lds + bOff[j][kk]);
    #pragma unroll
    for (int kk = 0; kk < 4; ++kk)
      #pragma unroll
      for (int i = 0; i < 3; ++i)
        #pragma unroll
        for (int j = 0; j < 2; ++j)
          acc[i][j] = __builtin_amdgcn_mfma_f32_16x16x32_bf16(
              af[i][kk], bfr[j][kk], acc[i][j], 0, 0, 0);
  };

  #pragma unroll 1
  for (int s = 0; s < 162; ++s) {
    stage(); adv();
    __syncthreads();                 // full drain: lockstep + LDS visible
    compute();
    __syncthreads();                 // readers done before next overwrite
  }

  // epilogue: D row = (lane>>4)*4+q (m dim), col = lane&15 (co dim)
  #pragma unroll
  for (int j = 0; j < 2; ++j) {
    int co = nt * 64 + wn + j * 16 + l15;
    float bb = bias[co];
    #pragma unroll
    for (int i = 0; i < 3; ++i) {
      int m0 = mt * 96 + wm + i * 16 + l4 * 4;
      #pragma unroll
      for (int q = 0; q < 4; ++q) {
        int m = m0 + q;
        int b = m / 36, s = m - b * 36;
        Y[((size_t)b * 256 + co) * 36 + s] = acc[i][j][q] + bb;
      }
    }
  }
}

// ---------- squash (in place on d_out): groups of 8 consecutive floats ----------
__global__ __launch_bounds__(256) void squash_k(float* __restrict__ Y) {
  const int g = blockIdx.x * 256 + threadIdx.x;  // 0..589823
  float4* p = (float4*)(Y + (size_t)g * 8);
  float4 a = p[0], b = p[1];
  float ns = a.x * a.x + a.y * a.y + a.z * a.z + a.w * a.w +
             b.x * b.x + b.y * b.y + b.z * b.z + b.w * b.w;
  float sc = ns / ((1.0f + ns) * (0.001f + sqrtf(ns)));
  a.x *= sc; a.y *= sc; a.z *= sc; a.w *= sc;
  b.x *= sc; b.y *= sc; b.z *= sc; b.w *= sc;
  p[0] = a; p[1] = b;
}

extern "C" void kernel_launch(void* const* d_in, const int* in_sizes, int n_in,
                              void* d_out, int out_size, void* d_ws, size_t ws_size,
                              hipStream_t stream) {
  const float* X = (const float*)d_in[0];     // [512,256,20,20]
  const float* W = (const float*)d_in[1];     // [256,256,9,9]
  const float* bias = (const float*)d_in[2];  // [256]
  float* Y = (float*)d_out;                   // [512,256,6,6] -> squashed

  unsigned short* Xt = (unsigned short*)d_ws;                 // 512*400*256 bf16
  unsigned short* Wt = Xt + (size_t)512 * 400 * 256;          // 81*256*256 bf16

  xform_x<<<512, 256, 0, stream>>>(X, Xt);
  xform_w<<<dim3(256, 2), 256, 0, stream>>>(W, Wt);
  conv_gemm<<<dim3(192, 4), 256, 0, stream>>>(Xt, Wt, bias, Y);
  squash_k<<<2304, 256, 0, stream>>>(Y);
}